// Round 16
// baseline (160.351 us; speedup 1.0000x reference)
//
#include <hip/hip_runtime.h>
#include <hip/hip_bf16.h>

// Sparse residual block: 2x (gather-GEMM-scatter conv 27x64x64 + BN + LeakyReLU) + residual.
// ABI: f32 in / f32 out. Internally bf16 MFMA (16x16x32) with f32 accumulation.
//
// R16 = R10 + in-loop address-chain elimination:
//  - all 54 per-tap A-gather byte offsets precomputed into VGPRs before the
//    k-loop (offL holds idx<<7; burst = 54 ds_read_b32 + add). In-loop LOAD_A
//    is 4 bare global loads (uniform base + 32b voffset + imm 64) — no VALU,
//    no lgkm inside the tile.
//  - 27 tiles fully unrolled (compile-time ring slots); sync discipline is
//    R10's verbatim: one s_barrier/tile, pinned issue, steady vmcnt(2).
//  - LDS union (offL | BN-reduce) -> 38.4 KB; 4 blocks/CU if VGPR <= 128.

#define N_VOX 100000
#define NCH 64
#define NK 27
#define ROWS 128
#define NBLK ((N_VOX + ROWS - 1) / ROWS)   // 782

typedef __hip_bfloat16 bf16;
typedef __attribute__((ext_vector_type(8))) short bf16x8;   // 8 bf16 = 4 VGPR
typedef __attribute__((ext_vector_type(4))) float f32x4;

__device__ __forceinline__ float b2f(short s) {
  unsigned u = ((unsigned)(unsigned short)s) << 16;
  return __builtin_bit_cast(float, u);
}
__device__ __forceinline__ short f2b(float f) {
  __hip_bfloat16 h = __float2bfloat16(f);
  return __builtin_bit_cast(short, h);
}

__device__ __forceinline__ void gload16(const void* g, void* l) {
  __builtin_amdgcn_global_load_lds(
      (const __attribute__((address_space(1))) void*)g,
      (__attribute__((address_space(3))) void*)l, 16, 0, 0);
}

// ---------------------------------------------------------------------------
// Cast feats f32 -> bf16, append zero sentinel row at index N.
__global__ void cast_feats(const float* __restrict__ feats, bf16* __restrict__ fbf) {
  const size_t i = ((size_t)blockIdx.x * 256 + threadIdx.x) * 8;
  if (i >= (size_t)(N_VOX + 1) * NCH) return;
  bf16x8 o;
  if (i < (size_t)N_VOX * NCH) {
    const f32x4 v0 = *reinterpret_cast<const f32x4*>(feats + i);
    const f32x4 v1 = *reinterpret_cast<const f32x4*>(feats + i + 4);
#pragma unroll
    for (int e = 0; e < 8; ++e) o[e] = f2b(e < 4 ? v0[e] : v1[e - 4]);
  } else {
#pragma unroll
    for (int e = 0; e < 8; ++e) o[e] = 0;
  }
  *reinterpret_cast<bf16x8*>((short*)fbf + i) = o;
}

// ---------------------------------------------------------------------------
// Pack W[k][c][o] (27,64,64 f32) into bf16 MFMA B-fragment order:
// frag id q = ((k*4 + j)*2 + kb)*64 + lane ; lane's 8 contiguous bf16:
//   B[kb*32 + (lane>>4)*8 + e][j*16 + (lane&15)]
__global__ void pack_w(const float* __restrict__ W1, const float* __restrict__ W2,
                       bf16* __restrict__ wp1, bf16* __restrict__ wp2) {
  const int t = blockIdx.x * 256 + threadIdx.x;
  const int half = NK * 4 * 2 * 64;  // 13824
  if (t >= 2 * half) return;
  const float* W = (t < half) ? W1 : W2;
  short* wp = (short*)((t < half) ? wp1 : wp2);
  const int q = (t < half) ? t : t - half;
  const int l  = q & 63;
  const int kb = (q >> 6) & 1;
  const int j  = (q >> 7) & 3;
  const int k  = q >> 9;
  const int oo = j * 16 + (l & 15);
  const int c0 = kb * 32 + (l >> 4) * 8;
  bf16x8 v;
#pragma unroll
  for (int e = 0; e < 8; ++e)
    v[e] = f2b(W[((size_t)k * 64 + c0 + e) * 64 + oo]);
  *reinterpret_cast<bf16x8*>(&wp[(size_t)q * 8]) = v;
}

// ---------------------------------------------------------------------------
// Gather-GEMM: y[n,o] = sum_k sum_c feat[nbr[k,n], c] * W[k,c,o]
// feat has N+1 rows (row N = zeros). 128 rows/block, 4 waves x 32 rows x 64 cols.
struct RedT { float S[4][NCH]; float Q[4][NCH]; };
union SmemU { int offL[NK * ROWS]; RedT red; };

__global__ __launch_bounds__(256, 3)
void conv_mfma(const bf16* __restrict__ feat, const bf16* __restrict__ wp,
               const int* __restrict__ nbr, bf16* __restrict__ y,
               float* __restrict__ part) {
  __shared__ short GB[3][4096];          // 3 x 8 KB B-fragment ring
  __shared__ SmemU U;                    // 13.8 KB: offL (pre-loop) | red (post)

  const int tid = threadIdx.x;
  const int lane = tid & 63;
  const int wv = tid >> 6;

  // XCD-chunked bijective swizzle (m204) for L2 gather locality.
  const int nwg = NBLK;                 // 782
  const int xcd = blockIdx.x & 7;
  const int pos = blockIdx.x >> 3;
  const int q8 = nwg >> 3, r8 = nwg & 7;
  const int bid = (xcd < r8 ? xcd * (q8 + 1) : r8 * (q8 + 1) + (xcd - r8) * q8) + pos;
  const int n0 = bid * ROWS;

  // Preload neighbor BYTE offsets (idx<<7) for all 27 taps (coalesced).
  for (int t = tid; t < NK * ROWS; t += 256) {
    const int k = t >> 7;
    const int rr = t & (ROWS - 1);
    const int idx = (n0 + rr < N_VOX) ? nbr[(size_t)k * N_VOX + n0 + rr] : N_VOX;
    U.offL[t] = idx << 7;                // row byte offset (128 B/row)
  }
  __syncthreads();   // offL ready; drains preload vmem

  const int r0 = wv * 32 + (lane & 15);  // row (h=0) this lane owns
  const unsigned ko16 = (unsigned)((lane >> 4) * 16);  // k-offset bytes

  // Burst: pull all 54 offsets into VGPRs (dead progressively as taps retire).
#define DECL27(M) M(0) M(1) M(2) M(3) M(4) M(5) M(6) M(7) M(8) M(9) M(10) \
  M(11) M(12) M(13) M(14) M(15) M(16) M(17) M(18) M(19) M(20) M(21) M(22) \
  M(23) M(24) M(25) M(26)
#define DECL_VO(t) unsigned vo##t##a, vo##t##b;
  DECL27(DECL_VO)
#define PRE_VO(t) \
  vo##t##a = (unsigned)U.offL[(t) * ROWS + r0] + ko16; \
  vo##t##b = (unsigned)U.offL[(t) * ROWS + r0 + 16] + ko16;
  DECL27(PRE_VO)

  f32x4 acc[2][4];
#pragma unroll
  for (int h = 0; h < 2; ++h)
#pragma unroll
    for (int j = 0; j < 4; ++j)
      acc[h][j] = (f32x4){0.f, 0.f, 0.f, 0.f};

  bf16x8 AE[4], AO[4];
  const char* fbase = (const char*)feat;

  // A frags {h}x{kb}: 4 bare gathered 16B loads (offsets precomputed).
#define LOAD_A_(A, va, vb)                                                  \
  {                                                                         \
    A[0] = *reinterpret_cast<const bf16x8*>(fbase + (size_t)(va));          \
    A[1] = *reinterpret_cast<const bf16x8*>(fbase + (size_t)(va) + 64);     \
    A[2] = *reinterpret_cast<const bf16x8*>(fbase + (size_t)(vb));          \
    A[3] = *reinterpret_cast<const bf16x8*>(fbase + (size_t)(vb) + 64);     \
  }

  // Stage B tap k into ring slot: 2 gload_lds per wave (dest uniform, m104).
#define STAGE_B(slot, k)                                                    \
  {                                                                         \
    const short* srcb = (const short*)wp + (size_t)(k) * 4096 +             \
                        (wv * 2) * 512 + lane * 8;                          \
    gload16((const void*)srcb, (void*)&GB[slot][(wv * 2) * 512]);           \
    gload16((const void*)(srcb + 512), (void*)&GB[slot][(wv * 2 + 1) * 512]); \
  }

#define MFMA_TAP(A, B)                                                      \
  _Pragma("unroll")                                                         \
  for (int h = 0; h < 2; ++h)                                               \
    _Pragma("unroll")                                                       \
    for (int j = 0; j < 4; ++j)                                             \
      _Pragma("unroll")                                                     \
      for (int kb = 0; kb < 2; ++kb)                                        \
        acc[h][j] = __builtin_amdgcn_mfma_f32_16x16x32_bf16(                \
            A[h * 2 + kb], B[j * 2 + kb], acc[h][j], 0, 0, 0);

#define READ_B(Bf, slot)                                                    \
  bf16x8 Bf[8];                                                             \
  _Pragma("unroll")                                                         \
  for (int f = 0; f < 8; ++f)                                               \
    Bf[f] = *reinterpret_cast<const bf16x8*>(&GB[slot][f * 512 + lane * 8]);

  // R10's tile verbatim: steady vmcnt(2) (FIFO completes Bst(t)+A(t), leaves
  // Bst(t+1)); ONE barrier; pinned issue of A(t+1) + Bstage(t+2); read+MFMA.
#define TILE(Acur, Aoth, vna, vnb, rdslot, stslot, kstg)                    \
  {                                                                         \
    asm volatile("s_waitcnt vmcnt(2)" ::: "memory");                        \
    __builtin_amdgcn_sched_barrier(0);                                      \
    __builtin_amdgcn_s_barrier();                                           \
    LOAD_A_(Aoth, vna, vnb)                                                 \
    STAGE_B(stslot, kstg)                                                   \
    __builtin_amdgcn_sched_barrier(0);                                      \
    READ_B(Bf, rdslot)                                                      \
    MFMA_TAP(Acur, Bf)                                                      \
  }

  // Prologue: queue = [B0:2][A0:4][B1:2] = 8 outstanding.
  STAGE_B(0, 0)
  LOAD_A_(AE, vo0a, vo0b)
  STAGE_B(1, 1)

  TILE(AE, AO, vo1a, vo1b, 0, 2, 2)     // t=0
  TILE(AO, AE, vo2a, vo2b, 1, 0, 3)     // t=1
  TILE(AE, AO, vo3a, vo3b, 2, 1, 4)     // t=2
  TILE(AO, AE, vo4a, vo4b, 0, 2, 5)     // t=3
  TILE(AE, AO, vo5a, vo5b, 1, 0, 6)     // t=4
  TILE(AO, AE, vo6a, vo6b, 2, 1, 7)     // t=5
  TILE(AE, AO, vo7a, vo7b, 0, 2, 8)     // t=6
  TILE(AO, AE, vo8a, vo8b, 1, 0, 9)     // t=7
  TILE(AE, AO, vo9a, vo9b, 2, 1, 10)    // t=8
  TILE(AO, AE, vo10a, vo10b, 0, 2, 11)  // t=9
  TILE(AE, AO, vo11a, vo11b, 1, 0, 12)  // t=10
  TILE(AO, AE, vo12a, vo12b, 2, 1, 13)  // t=11
  TILE(AE, AO, vo13a, vo13b, 0, 2, 14)  // t=12
  TILE(AO, AE, vo14a, vo14b, 1, 0, 15)  // t=13
  TILE(AE, AO, vo15a, vo15b, 2, 1, 16)  // t=14
  TILE(AO, AE, vo16a, vo16b, 0, 2, 17)  // t=15
  TILE(AE, AO, vo17a, vo17b, 1, 0, 18)  // t=16
  TILE(AO, AE, vo18a, vo18b, 2, 1, 19)  // t=17
  TILE(AE, AO, vo19a, vo19b, 0, 2, 20)  // t=18
  TILE(AO, AE, vo20a, vo20b, 1, 0, 21)  // t=19
  TILE(AE, AO, vo21a, vo21b, 2, 1, 22)  // t=20
  TILE(AO, AE, vo22a, vo22b, 0, 2, 23)  // t=21
  TILE(AE, AO, vo23a, vo23b, 1, 0, 24)  // t=22
  TILE(AO, AE, vo24a, vo24b, 2, 1, 25)  // t=23
  TILE(AE, AO, vo25a, vo25b, 0, 2, 26)  // t=24
  // t=25 (consume AO, load A26 -> AE, no stage left)
  {
    asm volatile("s_waitcnt vmcnt(2)" ::: "memory");
    __builtin_amdgcn_sched_barrier(0);
    __builtin_amdgcn_s_barrier();
    LOAD_A_(AE, vo26a, vo26b)
    __builtin_amdgcn_sched_barrier(0);
    READ_B(Bf, 1)
    MFMA_TAP(AO, Bf)
  }
  // t=26 (consume AE)
  {
    asm volatile("s_waitcnt vmcnt(0)" ::: "memory");
    __builtin_amdgcn_sched_barrier(0);
    __builtin_amdgcn_s_barrier();
    __builtin_amdgcn_sched_barrier(0);
    READ_B(Bf, 2)
    MFMA_TAP(AE, Bf)
  }

#undef DECL27
#undef DECL_VO
#undef PRE_VO
#undef LOAD_A_
#undef STAGE_B
#undef MFMA_TAP
#undef READ_B
#undef TILE

  // Store y (bf16). D layout: col = lane&15, row = (lane>>4)*4 + r  [m89]
#pragma unroll
  for (int h = 0; h < 2; ++h)
#pragma unroll
    for (int j = 0; j < 4; ++j) {
      const int col = j * 16 + (lane & 15);
#pragma unroll
      for (int r = 0; r < 4; ++r) {
        const int row = n0 + wv * 32 + h * 16 + (lane >> 4) * 4 + r;
        if (row < N_VOX) ((short*)y)[(size_t)row * NCH + col] = f2b(acc[h][j][r]);
      }
    }

  // BN partial sums: per-channel sum and sum-of-squares over this block's rows
  // (zero-padded tail rows contribute 0). offL is dead; reuse LDS as red.
  __syncthreads();
#pragma unroll
  for (int j = 0; j < 4; ++j) {
    float s1 = 0.f, s2 = 0.f;
#pragma unroll
    for (int h = 0; h < 2; ++h)
#pragma unroll
      for (int r = 0; r < 4; ++r) {
        const float v = acc[h][j][r];
        s1 += v;
        s2 += v * v;
      }
    s1 += __shfl_xor(s1, 16); s2 += __shfl_xor(s2, 16);
    s1 += __shfl_xor(s1, 32); s2 += __shfl_xor(s2, 32);
    if (lane < 16) {
      U.red.S[wv][j * 16 + lane] = s1;
      U.red.Q[wv][j * 16 + lane] = s2;
    }
  }
  __syncthreads();
  if (tid < NCH) {
    const float s1 = U.red.S[0][tid] + U.red.S[1][tid] + U.red.S[2][tid] + U.red.S[3][tid];
    const float s2 = U.red.Q[0][tid] + U.red.Q[1][tid] + U.red.Q[2][tid] + U.red.Q[3][tid];
    part[(size_t)blockIdx.x * 128 + tid] = s1;
    part[(size_t)blockIdx.x * 128 + 64 + tid] = s2;
  }
}

// ---------------------------------------------------------------------------
// Reduce per-block partials -> per-channel (a, shift): a = g*rsqrt(var+eps),
// shift = b - mean*a.  Grid: 64 blocks (one per channel) x 256 threads.
__global__ void finalize(const float* __restrict__ part, int nblk,
                         const float* __restrict__ g, const float* __restrict__ b,
                         float* __restrict__ ab) {
  __shared__ float r1[256], r2[256];
  const int c = blockIdx.x;
  const int t = threadIdx.x;
  float s1 = 0.f, s2 = 0.f;
  for (int bb = t; bb < nblk; bb += 256) {
    s1 += part[(size_t)bb * 128 + c];
    s2 += part[(size_t)bb * 128 + 64 + c];
  }
  r1[t] = s1; r2[t] = s2;
  __syncthreads();
  for (int off = 128; off > 0; off >>= 1) {
    if (t < off) { r1[t] += r1[t + off]; r2[t] += r2[t + off]; }
    __syncthreads();
  }
  if (t == 0) {
    const float m = r1[0] / (float)N_VOX;
    const float v = r2[0] / (float)N_VOX - m * m;
    const float a = g[c] * rsqrtf(v + 1e-5f);
    const float sh = b[c] - m * a;
    ab[c] = a;
    ab[64 + c] = sh;
  }
}

// ---------------------------------------------------------------------------
// z[n,c] = lrelu(y[n,c]*a[c]+s[c]) as bf16; row N (sentinel) = 0.
__global__ void bn_act(const bf16* __restrict__ y, const float* __restrict__ ab,
                       bf16* __restrict__ z) {
  const size_t i = ((size_t)blockIdx.x * 256 + threadIdx.x) * 8;
  if (i >= (size_t)(N_VOX + 1) * NCH) return;
  const int col = (int)(i & 63);
  bf16x8 o;
  if (i < (size_t)N_VOX * NCH) {
    const bf16x8 v = *reinterpret_cast<const bf16x8*>((const short*)y + i);
#pragma unroll
    for (int e = 0; e < 8; ++e) {
      float x = b2f(v[e]) * ab[col + e] + ab[64 + col + e];
      x = x < 0.f ? 0.01f * x : x;
      o[e] = f2b(x);
    }
  } else {
#pragma unroll
    for (int e = 0; e < 8; ++e) o[e] = 0;
  }
  *reinterpret_cast<bf16x8*>((short*)z + i) = o;
}

// ---------------------------------------------------------------------------
// out[n,c] = lrelu( feats[n,c] + lrelu(y[n,c]*a[c]+s[c]) ) as f32.
// Grid exact: N*C/2048 = 3125 blocks, no tail.
__global__ void bn_act_res(const bf16* __restrict__ y, const float* __restrict__ ab,
                           const float* __restrict__ feats, float* __restrict__ out) {
  const size_t i = ((size_t)blockIdx.x * 256 + threadIdx.x) * 8;
  const int col = (int)(i & 63);
  const bf16x8 v = *reinterpret_cast<const bf16x8*>((const short*)y + i);
  const f32x4 s0 = *reinterpret_cast<const f32x4*>(feats + i);
  const f32x4 s1 = *reinterpret_cast<const f32x4*>(feats + i + 4);
  f32x4 o0, o1;
#pragma unroll
  for (int e = 0; e < 8; ++e) {
    float x = b2f(v[e]) * ab[col + e] + ab[64 + col + e];
    x = x < 0.f ? 0.01f * x : x;                    // lrelu(bn2)
    float r = (e < 4 ? s0[e] : s1[e - 4]) + x;      // + skip
    r = r < 0.f ? 0.01f * r : r;                    // final lrelu
    if (e < 4) o0[e] = r; else o1[e - 4] = r;
  }
  *reinterpret_cast<f32x4*>(out + i) = o0;
  *reinterpret_cast<f32x4*>(out + i + 4) = o1;
}

// ---------------------------------------------------------------------------
extern "C" void kernel_launch(void* const* d_in, const int* in_sizes, int n_in,
                              void* d_out, int out_size, void* d_ws, size_t ws_size,
                              hipStream_t stream) {
  const float* feats = (const float*)d_in[0];
  const float* W1 = (const float*)d_in[1];
  const float* g1 = (const float*)d_in[2];
  const float* b1 = (const float*)d_in[3];
  const float* W2 = (const float*)d_in[4];
  const float* g2 = (const float*)d_in[5];
  const float* b2 = (const float*)d_in[6];
  const int* nbr = (const int*)d_in[7];
  float* out = (float*)d_out;

  char* p = (char*)d_ws;
  bf16* fbf = (bf16*)p; p += (size_t)(N_VOX + 1) * NCH * 2;   // 12.80 MB
  bf16* ybf = (bf16*)p; p += (size_t)N_VOX * NCH * 2;         // 12.80 MB
  bf16* z = (bf16*)p;   p += (size_t)(N_VOX + 1) * NCH * 2;   // 12.80 MB
  bf16* wp1 = (bf16*)p; p += 442368;
  bf16* wp2 = (bf16*)p; p += 442368;
  float* part = (float*)p; p += (size_t)NBLK * 128 * 4;       // 400 KB
  float* ab1 = (float*)p; p += 512;
  float* ab2 = (float*)p; p += 512;

  const int cast_blocks = (int)(((size_t)(N_VOX + 1) * NCH / 8 + 255) / 256);  // 3126

  cast_feats<<<cast_blocks, 256, 0, stream>>>(feats, fbf);
  pack_w<<<108, 256, 0, stream>>>(W1, W2, wp1, wp2);

  conv_mfma<<<NBLK, 256, 0, stream>>>(fbf, wp1, nbr, ybf, part);
  finalize<<<64, 256, 0, stream>>>(part, NBLK, g1, b1, ab1);
  bn_act<<<cast_blocks, 256, 0, stream>>>(ybf, ab1, z);

  conv_mfma<<<NBLK, 256, 0, stream>>>(z, wp2, nbr, ybf, part);
  finalize<<<64, 256, 0, stream>>>(part, NBLK, g2, b2, ab2);
  bn_act_res<<<(N_VOX * NCH / 8) / 256, 256, 0, stream>>>(ybf, ab2, feats, out);
}

// Round 20
// 132.831 us; speedup vs baseline: 1.2072x; 1.2072x over previous
//
#include <hip/hip_runtime.h>
#include <hip/hip_bf16.h>

// Sparse residual block: 2x (gather-GEMM-scatter conv 27x64x64 + BN + LeakyReLU) + residual.
// ABI: f32 in / f32 out. Internally bf16 MFMA (16x16x32) with f32 accumulation.
//
// R17 = R10 (proven 134.7us base) + coalesced y-store:
//  - k-loop, ring-3 B, single barrier/tile, pinned issue, steady vmcnt(2):
//    VERBATIM R10.
//  - y-epilogue: acc -> LDS bounce (16KB, reuses GB[0..1], dead after tap 26)
//    -> 1024 contiguous bf16x8 chunks (32 coalesced store insts/block) instead
//    of 512 scalar short-stores (2048 scattered 32B segments/block). R15's
//    K-split datum showed conv is throughput-bound on shared vmem traffic;
//    scattered stores were as many segments as the whole gather phase.

#define N_VOX 100000
#define NCH 64
#define NK 27
#define ROWS 128
#define NBLK ((N_VOX + ROWS - 1) / ROWS)   // 782

typedef __hip_bfloat16 bf16;
typedef __attribute__((ext_vector_type(8))) short bf16x8;   // 8 bf16 = 4 VGPR
typedef __attribute__((ext_vector_type(4))) float f32x4;

__device__ __forceinline__ float b2f(short s) {
  unsigned u = ((unsigned)(unsigned short)s) << 16;
  return __builtin_bit_cast(float, u);
}
__device__ __forceinline__ short f2b(float f) {
  __hip_bfloat16 h = __float2bfloat16(f);
  return __builtin_bit_cast(short, h);
}

__device__ __forceinline__ void gload16(const void* g, void* l) {
  __builtin_amdgcn_global_load_lds(
      (const __attribute__((address_space(1))) void*)g,
      (__attribute__((address_space(3))) void*)l, 16, 0, 0);
}

// ---------------------------------------------------------------------------
// Cast feats f32 -> bf16, append zero sentinel row at index N.
__global__ void cast_feats(const float* __restrict__ feats, bf16* __restrict__ fbf) {
  const size_t i = ((size_t)blockIdx.x * 256 + threadIdx.x) * 8;
  if (i >= (size_t)(N_VOX + 1) * NCH) return;
  bf16x8 o;
  if (i < (size_t)N_VOX * NCH) {
    const f32x4 v0 = *reinterpret_cast<const f32x4*>(feats + i);
    const f32x4 v1 = *reinterpret_cast<const f32x4*>(feats + i + 4);
#pragma unroll
    for (int e = 0; e < 8; ++e) o[e] = f2b(e < 4 ? v0[e] : v1[e - 4]);
  } else {
#pragma unroll
    for (int e = 0; e < 8; ++e) o[e] = 0;
  }
  *reinterpret_cast<bf16x8*>((short*)fbf + i) = o;
}

// ---------------------------------------------------------------------------
// Pack W[k][c][o] (27,64,64 f32) into bf16 MFMA B-fragment order:
// frag id q = ((k*4 + j)*2 + kb)*64 + lane ; lane's 8 contiguous bf16:
//   B[kb*32 + (lane>>4)*8 + e][j*16 + (lane&15)]
__global__ void pack_w(const float* __restrict__ W1, const float* __restrict__ W2,
                       bf16* __restrict__ wp1, bf16* __restrict__ wp2) {
  const int t = blockIdx.x * 256 + threadIdx.x;
  const int half = NK * 4 * 2 * 64;  // 13824
  if (t >= 2 * half) return;
  const float* W = (t < half) ? W1 : W2;
  short* wp = (short*)((t < half) ? wp1 : wp2);
  const int q = (t < half) ? t : t - half;
  const int l  = q & 63;
  const int kb = (q >> 6) & 1;
  const int j  = (q >> 7) & 3;
  const int k  = q >> 9;
  const int oo = j * 16 + (l & 15);
  const int c0 = kb * 32 + (l >> 4) * 8;
  bf16x8 v;
#pragma unroll
  for (int e = 0; e < 8; ++e)
    v[e] = f2b(W[((size_t)k * 64 + c0 + e) * 64 + oo]);
  *reinterpret_cast<bf16x8*>(&wp[(size_t)q * 8]) = v;
}

// ---------------------------------------------------------------------------
// Gather-GEMM: y[n,o] = sum_k sum_c feat[nbr[k,n], c] * W[k,c,o]
// feat has N+1 rows (row N = zeros). 128 rows/block, 4 waves x 32 rows x 64 cols.
__global__ __launch_bounds__(256, 3)
void conv_mfma(const bf16* __restrict__ feat, const bf16* __restrict__ wp,
               const int* __restrict__ nbr, bf16* __restrict__ y,
               float* __restrict__ part) {
  __shared__ short GB[3][4096];          // 3 x 8 KB B-fragment ring (also y-stage)
  __shared__ int nbrL[NK * ROWS];        // 13.5 KB neighbor indices
  __shared__ float redS[4][NCH];
  __shared__ float redQ[4][NCH];

  const int tid = threadIdx.x;
  const int lane = tid & 63;
  const int wv = tid >> 6;

  // XCD-chunked bijective swizzle (m204) for L2 gather locality.
  const int nwg = NBLK;                 // 782
  const int xcd = blockIdx.x & 7;
  const int pos = blockIdx.x >> 3;
  const int q8 = nwg >> 3, r8 = nwg & 7;
  const int bid = (xcd < r8 ? xcd * (q8 + 1) : r8 * (q8 + 1) + (xcd - r8) * q8) + pos;
  const int n0 = bid * ROWS;

  // Preload all 27*128 neighbor indices for this block (coalesced, 14 rounds).
  for (int t = tid; t < NK * ROWS; t += 256) {
    const int k = t >> 7;
    const int rr = t & (ROWS - 1);
    nbrL[t] = (n0 + rr < N_VOX) ? nbr[(size_t)k * N_VOX + n0 + rr] : N_VOX;
  }
  __syncthreads();   // nbrL ready; drains preload vmem

  const int r0 = wv * 32 + (lane & 15);  // row (h=0) this lane owns
  const int koff = (lane >> 4) * 8;      // k-element offset within a row

  f32x4 acc[2][4];
#pragma unroll
  for (int h = 0; h < 2; ++h)
#pragma unroll
    for (int j = 0; j < 4; ++j)
      acc[h][j] = (f32x4){0.f, 0.f, 0.f, 0.f};

  bf16x8 AE[4], AO[4];

  // A frags {h}x{kb}: per-lane gathered 16B loads (layout verified, absmax ok).
#define LOAD_A(A, k)                                                        \
  {                                                                         \
    const int i0 = nbrL[(k) * ROWS + r0];                                   \
    const int i1 = nbrL[(k) * ROWS + r0 + 16];                              \
    A[0] = *reinterpret_cast<const bf16x8*>(feat + (size_t)i0 * 64 + koff); \
    A[1] = *reinterpret_cast<const bf16x8*>(feat + (size_t)i0 * 64 + 32 + koff); \
    A[2] = *reinterpret_cast<const bf16x8*>(feat + (size_t)i1 * 64 + koff); \
    A[3] = *reinterpret_cast<const bf16x8*>(feat + (size_t)i1 * 64 + 32 + koff); \
  }

  // Stage B tile k into ring slot: 2 gload_lds per wave (dest uniform, m104).
#define STAGE_B(slot, k)                                                    \
  {                                                                         \
    const short* srcb = (const short*)wp + (size_t)(k) * 4096 +             \
                        (wv * 2) * 512 + lane * 8;                          \
    gload16((const void*)srcb, (void*)&GB[slot][(wv * 2) * 512]);           \
    gload16((const void*)(srcb + 512), (void*)&GB[slot][(wv * 2 + 1) * 512]); \
  }

#define MFMA_TAP(A, B)                                                      \
  _Pragma("unroll")                                                         \
  for (int h = 0; h < 2; ++h)                                               \
    _Pragma("unroll")                                                       \
    for (int j = 0; j < 4; ++j)                                             \
      _Pragma("unroll")                                                     \
      for (int kb = 0; kb < 2; ++kb)                                        \
        acc[h][j] = __builtin_amdgcn_mfma_f32_16x16x32_bf16(                \
            A[h * 2 + kb], B[j * 2 + kb], acc[h][j], 0, 0, 0);

  // One tile. Issue order: A(t+1) [4 loads] then Bstage(t+2) [2] -> steady
  // wait vmcnt(2) => A aged 1 tile, Bstage aged 2 tiles. No drain in loop.
#define TILE_STEP(Acur, Aoth, t)                                            \
  {                                                                         \
    if ((t) < NK - 1) { asm volatile("s_waitcnt vmcnt(2)" ::: "memory"); }  \
    else              { asm volatile("s_waitcnt vmcnt(0)" ::: "memory"); }  \
    __builtin_amdgcn_sched_barrier(0);                                      \
    __builtin_amdgcn_s_barrier();                                           \
    if ((t) + 1 < NK) LOAD_A(Aoth, (t) + 1)                                 \
    if ((t) + 2 < NK) {                                                     \
      const int stslot = ((t) + 2) % 3;                                     \
      STAGE_B(stslot, (t) + 2)                                              \
    }                                                                       \
    __builtin_amdgcn_sched_barrier(0); /* pin loads above the MFMAs */      \
    bf16x8 Bf[8];                                                           \
    const int rdslot = (t) % 3;                                             \
    _Pragma("unroll")                                                       \
    for (int f = 0; f < 8; ++f)                                             \
      Bf[f] = *reinterpret_cast<const bf16x8*>(                             \
          &GB[rdslot][f * 512 + lane * 8]);                                 \
    MFMA_TAP(Acur, Bf)                                                      \
  }

  // Prologue: queue = [B0:2][A0:4][B1:2] = 8 outstanding.
  STAGE_B(0, 0)
  LOAD_A(AE, 0)
  STAGE_B(1, 1)

#pragma unroll 1
  for (int j = 0; j < 13; ++j) {
    const int t = 2 * j;
    TILE_STEP(AE, AO, t)
    TILE_STEP(AO, AE, t + 1)
  }
  TILE_STEP(AE, AO, 26)   // tail tap (vmcnt(0) path)

#undef LOAD_A
#undef STAGE_B
#undef MFMA_TAP
#undef TILE_STEP

  // -------------------------------------------------------------------------
  // Coalesced y-store: bounce acc through LDS (reuse GB[0..1] = 16KB, dead).
  // D layout: col = lane&15 (+j*16), row = wv*32 + h*16 + (lane>>4)*4 + r [m89]
  __syncthreads();   // all waves done with GB reads (tap 26 used GB[2] only)
  {
    short* Ys = &GB[0][0];   // [128][64] shorts = 16 KB
#pragma unroll
    for (int h = 0; h < 2; ++h)
#pragma unroll
      for (int j = 0; j < 4; ++j) {
        const int col = j * 16 + (lane & 15);
#pragma unroll
        for (int r = 0; r < 4; ++r) {
          const int lrow = wv * 32 + h * 16 + (lane >> 4) * 4 + r;
          Ys[lrow * 64 + col] = f2b(acc[h][j][r]);
        }
      }
    __syncthreads();
    // 1024 chunks of 8 shorts; 256 threads x 4 rounds, fully coalesced.
#pragma unroll
    for (int pth = 0; pth < 4; ++pth) {
      const int c = pth * 256 + tid;
      const int grow = n0 + (c >> 3);
      if (grow < N_VOX) {
        const bf16x8 v = *reinterpret_cast<const bf16x8*>(&Ys[c * 8]);
        *reinterpret_cast<bf16x8*>((short*)y + (size_t)grow * 64 + (c & 7) * 8) = v;
      }
    }
  }

  // BN partial sums: per-channel sum and sum-of-squares over this block's rows
  // (zero-padded tail rows contribute 0).
#pragma unroll
  for (int j = 0; j < 4; ++j) {
    float s1 = 0.f, s2 = 0.f;
#pragma unroll
    for (int h = 0; h < 2; ++h)
#pragma unroll
      for (int r = 0; r < 4; ++r) {
        const float v = acc[h][j][r];
        s1 += v;
        s2 += v * v;
      }
    s1 += __shfl_xor(s1, 16); s2 += __shfl_xor(s2, 16);
    s1 += __shfl_xor(s1, 32); s2 += __shfl_xor(s2, 32);
    if (lane < 16) {
      redS[wv][j * 16 + lane] = s1;
      redQ[wv][j * 16 + lane] = s2;
    }
  }
  __syncthreads();
  if (tid < NCH) {
    const float s1 = redS[0][tid] + redS[1][tid] + redS[2][tid] + redS[3][tid];
    const float s2 = redQ[0][tid] + redQ[1][tid] + redQ[2][tid] + redQ[3][tid];
    part[(size_t)blockIdx.x * 128 + tid] = s1;
    part[(size_t)blockIdx.x * 128 + 64 + tid] = s2;
  }
}

// ---------------------------------------------------------------------------
// Reduce per-block partials -> per-channel (a, shift): a = g*rsqrt(var+eps),
// shift = b - mean*a.  Grid: 64 blocks (one per channel) x 256 threads.
__global__ void finalize(const float* __restrict__ part, int nblk,
                         const float* __restrict__ g, const float* __restrict__ b,
                         float* __restrict__ ab) {
  __shared__ float r1[256], r2[256];
  const int c = blockIdx.x;
  const int t = threadIdx.x;
  float s1 = 0.f, s2 = 0.f;
  for (int bb = t; bb < nblk; bb += 256) {
    s1 += part[(size_t)bb * 128 + c];
    s2 += part[(size_t)bb * 128 + 64 + c];
  }
  r1[t] = s1; r2[t] = s2;
  __syncthreads();
  for (int off = 128; off > 0; off >>= 1) {
    if (t < off) { r1[t] += r1[t + off]; r2[t] += r2[t + off]; }
    __syncthreads();
  }
  if (t == 0) {
    const float m = r1[0] / (float)N_VOX;
    const float v = r2[0] / (float)N_VOX - m * m;
    const float a = g[c] * rsqrtf(v + 1e-5f);
    const float sh = b[c] - m * a;
    ab[c] = a;
    ab[64 + c] = sh;
  }
}

// ---------------------------------------------------------------------------
// z[n,c] = lrelu(y[n,c]*a[c]+s[c]) as bf16; row N (sentinel) = 0.
__global__ void bn_act(const bf16* __restrict__ y, const float* __restrict__ ab,
                       bf16* __restrict__ z) {
  const size_t i = ((size_t)blockIdx.x * 256 + threadIdx.x) * 8;
  if (i >= (size_t)(N_VOX + 1) * NCH) return;
  const int col = (int)(i & 63);
  bf16x8 o;
  if (i < (size_t)N_VOX * NCH) {
    const bf16x8 v = *reinterpret_cast<const bf16x8*>((const short*)y + i);
#pragma unroll
    for (int e = 0; e < 8; ++e) {
      float x = b2f(v[e]) * ab[col + e] + ab[64 + col + e];
      x = x < 0.f ? 0.01f * x : x;
      o[e] = f2b(x);
    }
  } else {
#pragma unroll
    for (int e = 0; e < 8; ++e) o[e] = 0;
  }
  *reinterpret_cast<bf16x8*>((short*)z + i) = o;
}

// ---------------------------------------------------------------------------
// out[n,c] = lrelu( feats[n,c] + lrelu(y[n,c]*a[c]+s[c]) ) as f32.
// Grid exact: N*C/2048 = 3125 blocks, no tail.
__global__ void bn_act_res(const bf16* __restrict__ y, const float* __restrict__ ab,
                           const float* __restrict__ feats, float* __restrict__ out) {
  const size_t i = ((size_t)blockIdx.x * 256 + threadIdx.x) * 8;
  const int col = (int)(i & 63);
  const bf16x8 v = *reinterpret_cast<const bf16x8*>((const short*)y + i);
  const f32x4 s0 = *reinterpret_cast<const f32x4*>(feats + i);
  const f32x4 s1 = *reinterpret_cast<const f32x4*>(feats + i + 4);
  f32x4 o0, o1;
#pragma unroll
  for (int e = 0; e < 8; ++e) {
    float x = b2f(v[e]) * ab[col + e] + ab[64 + col + e];
    x = x < 0.f ? 0.01f * x : x;                    // lrelu(bn2)
    float r = (e < 4 ? s0[e] : s1[e - 4]) + x;      // + skip
    r = r < 0.f ? 0.01f * r : r;                    // final lrelu
    if (e < 4) o0[e] = r; else o1[e - 4] = r;
  }
  *reinterpret_cast<f32x4*>(out + i) = o0;
  *reinterpret_cast<f32x4*>(out + i + 4) = o1;
}

// ---------------------------------------------------------------------------
extern "C" void kernel_launch(void* const* d_in, const int* in_sizes, int n_in,
                              void* d_out, int out_size, void* d_ws, size_t ws_size,
                              hipStream_t stream) {
  const float* feats = (const float*)d_in[0];
  const float* W1 = (const float*)d_in[1];
  const float* g1 = (const float*)d_in[2];
  const float* b1 = (const float*)d_in[3];
  const float* W2 = (const float*)d_in[4];
  const float* g2 = (const float*)d_in[5];
  const float* b2 = (const float*)d_in[6];
  const int* nbr = (const int*)d_in[7];
  float* out = (float*)d_out;

  char* p = (char*)d_ws;
  bf16* fbf = (bf16*)p; p += (size_t)(N_VOX + 1) * NCH * 2;   // 12.80 MB
  bf16* ybf = (bf16*)p; p += (size_t)N_VOX * NCH * 2;         // 12.80 MB
  bf16* z = (bf16*)p;   p += (size_t)(N_VOX + 1) * NCH * 2;   // 12.80 MB
  bf16* wp1 = (bf16*)p; p += 442368;
  bf16* wp2 = (bf16*)p; p += 442368;
  float* part = (float*)p; p += (size_t)NBLK * 128 * 4;       // 400 KB
  float* ab1 = (float*)p; p += 512;
  float* ab2 = (float*)p; p += 512;

  const int cast_blocks = (int)(((size_t)(N_VOX + 1) * NCH / 8 + 255) / 256);  // 3126

  cast_feats<<<cast_blocks, 256, 0, stream>>>(feats, fbf);
  pack_w<<<108, 256, 0, stream>>>(W1, W2, wp1, wp2);

  conv_mfma<<<NBLK, 256, 0, stream>>>(fbf, wp1, nbr, ybf, part);
  finalize<<<64, 256, 0, stream>>>(part, NBLK, g1, b1, ab1);
  bn_act<<<cast_blocks, 256, 0, stream>>>(ybf, ab1, z);

  conv_mfma<<<NBLK, 256, 0, stream>>>(z, wp2, nbr, ybf, part);
  finalize<<<64, 256, 0, stream>>>(part, NBLK, g2, b2, ab2);
  bn_act_res<<<(N_VOX * NCH / 8) / 256, 256, 0, stream>>>(ybf, ab2, feats, out);
}

// Round 21
// 129.413 us; speedup vs baseline: 1.2391x; 1.0264x over previous
//
#include <hip/hip_runtime.h>
#include <hip/hip_bf16.h>

// Sparse residual block: 2x (gather-GEMM-scatter conv 27x64x64 + BN + LeakyReLU) + residual.
// ABI: f32 in / f32 out. Internally bf16 MFMA (16x16x32) with f32 accumulation.
//
// R21 = R10 schedule on 256-row blocks (64 rows/wave, ILP axis):
//  - 4 waves x 64 rows x 64 cols; 32 MFMA per tap per wave (2x chain amortize).
//  - B-LDS-read traffic per row HALVES (R7 showed B ds_reads dominate LDS pipe);
//    barriers per row halve; nbr preload per row halves.
//  - vmcnt discipline = R10 proof transplanted: per tile issue A(t+1):8 +
//    Bst(t+2):2; steady wait vmcnt(2) completes Bst(t)+A(t) (aged 1-2 tiles),
//    leaves Bst(t+1) in flight; ONE s_barrier/tile; ring-3 B.
//  - TLP drops to ~6 waves/CU (grid 391): accepted risk — R15 proved TLP
//    is not the binding resource.

#define N_VOX 100000
#define NCH 64
#define NK 27
#define ROWS 256
#define NBLK ((N_VOX + ROWS - 1) / ROWS)   // 391

typedef __hip_bfloat16 bf16;
typedef __attribute__((ext_vector_type(8))) short bf16x8;   // 8 bf16 = 4 VGPR
typedef __attribute__((ext_vector_type(4))) float f32x4;

__device__ __forceinline__ float b2f(short s) {
  unsigned u = ((unsigned)(unsigned short)s) << 16;
  return __builtin_bit_cast(float, u);
}
__device__ __forceinline__ short f2b(float f) {
  __hip_bfloat16 h = __float2bfloat16(f);
  return __builtin_bit_cast(short, h);
}

__device__ __forceinline__ void gload16(const void* g, void* l) {
  __builtin_amdgcn_global_load_lds(
      (const __attribute__((address_space(1))) void*)g,
      (__attribute__((address_space(3))) void*)l, 16, 0, 0);
}

// ---------------------------------------------------------------------------
// Cast feats f32 -> bf16, append zero sentinel row at index N.
__global__ void cast_feats(const float* __restrict__ feats, bf16* __restrict__ fbf) {
  const size_t i = ((size_t)blockIdx.x * 256 + threadIdx.x) * 8;
  if (i >= (size_t)(N_VOX + 1) * NCH) return;
  bf16x8 o;
  if (i < (size_t)N_VOX * NCH) {
    const f32x4 v0 = *reinterpret_cast<const f32x4*>(feats + i);
    const f32x4 v1 = *reinterpret_cast<const f32x4*>(feats + i + 4);
#pragma unroll
    for (int e = 0; e < 8; ++e) o[e] = f2b(e < 4 ? v0[e] : v1[e - 4]);
  } else {
#pragma unroll
    for (int e = 0; e < 8; ++e) o[e] = 0;
  }
  *reinterpret_cast<bf16x8*>((short*)fbf + i) = o;
}

// ---------------------------------------------------------------------------
// Pack W[k][c][o] (27,64,64 f32) into bf16 MFMA B-fragment order:
// frag id q = ((k*4 + j)*2 + kb)*64 + lane ; lane's 8 contiguous bf16:
//   B[kb*32 + (lane>>4)*8 + e][j*16 + (lane&15)]
__global__ void pack_w(const float* __restrict__ W1, const float* __restrict__ W2,
                       bf16* __restrict__ wp1, bf16* __restrict__ wp2) {
  const int t = blockIdx.x * 256 + threadIdx.x;
  const int half = NK * 4 * 2 * 64;  // 13824
  if (t >= 2 * half) return;
  const float* W = (t < half) ? W1 : W2;
  short* wp = (short*)((t < half) ? wp1 : wp2);
  const int q = (t < half) ? t : t - half;
  const int l  = q & 63;
  const int kb = (q >> 6) & 1;
  const int j  = (q >> 7) & 3;
  const int k  = q >> 9;
  const int oo = j * 16 + (l & 15);
  const int c0 = kb * 32 + (l >> 4) * 8;
  bf16x8 v;
#pragma unroll
  for (int e = 0; e < 8; ++e)
    v[e] = f2b(W[((size_t)k * 64 + c0 + e) * 64 + oo]);
  *reinterpret_cast<bf16x8*>(&wp[(size_t)q * 8]) = v;
}

// ---------------------------------------------------------------------------
// Gather-GEMM: y[n,o] = sum_k sum_c feat[nbr[k,n], c] * W[k,c,o]
// feat has N+1 rows (row N = zeros). 256 rows/block, 4 waves x 64 rows x 64 cols.
__global__ __launch_bounds__(256, 2)
void conv_mfma(const bf16* __restrict__ feat, const bf16* __restrict__ wp,
               const int* __restrict__ nbr, bf16* __restrict__ y,
               float* __restrict__ part) {
  __shared__ short GB[3][4096];          // 3 x 8 KB B-fragment ring
  __shared__ int nbrL[NK * ROWS];        // 27 KB neighbor indices
  __shared__ float redS[4][NCH];
  __shared__ float redQ[4][NCH];

  const int tid = threadIdx.x;
  const int lane = tid & 63;
  const int wv = tid >> 6;

  // XCD-chunked bijective swizzle (m204) for L2 gather locality.
  const int nwg = NBLK;                 // 391
  const int xcd = blockIdx.x & 7;
  const int pos = blockIdx.x >> 3;
  const int q8 = nwg >> 3, r8 = nwg & 7;
  const int bid = (xcd < r8 ? xcd * (q8 + 1) : r8 * (q8 + 1) + (xcd - r8) * q8) + pos;
  const int n0 = bid * ROWS;

  // Preload all 27*256 neighbor indices for this block (coalesced, 27 rounds).
  for (int t = tid; t < NK * ROWS; t += 256) {
    const int k = t >> 8;
    const int rr = t & (ROWS - 1);
    nbrL[t] = (n0 + rr < N_VOX) ? nbr[(size_t)k * N_VOX + n0 + rr] : N_VOX;
  }
  __syncthreads();   // nbrL ready; drains preload vmem

  const int r0 = wv * 64 + (lane & 15);  // base row (g=0) this lane owns
  const int koff = (lane >> 4) * 8;      // k-element offset within a row

  f32x4 acc[4][4];
#pragma unroll
  for (int g = 0; g < 4; ++g)
#pragma unroll
    for (int j = 0; j < 4; ++j)
      acc[g][j] = (f32x4){0.f, 0.f, 0.f, 0.f};

  bf16x8 AE[8], AO[8];

  // A frags {g=row-group 0..3} x {kb 0..1}: per-lane gathered 16B loads.
#define LOAD_A(A, k)                                                        \
  {                                                                         \
    _Pragma("unroll")                                                       \
    for (int g = 0; g < 4; ++g) {                                           \
      const int ig = nbrL[(k) * ROWS + r0 + 16 * g];                        \
      A[g * 2 + 0] = *reinterpret_cast<const bf16x8*>(                      \
          feat + (size_t)ig * 64 + koff);                                   \
      A[g * 2 + 1] = *reinterpret_cast<const bf16x8*>(                      \
          feat + (size_t)ig * 64 + 32 + koff);                              \
    }                                                                       \
  }

  // Stage B tile k into ring slot: 2 gload_lds per wave (dest uniform, m104).
#define STAGE_B(slot, k)                                                    \
  {                                                                         \
    const short* srcb = (const short*)wp + (size_t)(k) * 4096 +             \
                        (wv * 2) * 512 + lane * 8;                          \
    gload16((const void*)srcb, (void*)&GB[slot][(wv * 2) * 512]);           \
    gload16((const void*)(srcb + 512), (void*)&GB[slot][(wv * 2 + 1) * 512]); \
  }

#define MFMA_TAP(A, B)                                                      \
  _Pragma("unroll")                                                         \
  for (int g = 0; g < 4; ++g)                                               \
    _Pragma("unroll")                                                       \
    for (int j = 0; j < 4; ++j)                                             \
      _Pragma("unroll")                                                     \
      for (int kb = 0; kb < 2; ++kb)                                        \
        acc[g][j] = __builtin_amdgcn_mfma_f32_16x16x32_bf16(                \
            A[g * 2 + kb], B[j * 2 + kb], acc[g][j], 0, 0, 0);

  // One tile. Issue A(t+1):8 then Bstage(t+2):2 -> at tile t's wait the queue
  // is [Bst(t):2, A(t):8, Bst(t+1):2]; vmcnt(2) completes Bst(t)+A(t), leaves
  // Bst(t+1). Bst(t) completes before this tile's barrier -> visible to all.
#define TILE_STEP(Acur, Aoth, t)                                            \
  {                                                                         \
    if ((t) < NK - 1) { asm volatile("s_waitcnt vmcnt(2)" ::: "memory"); }  \
    else              { asm volatile("s_waitcnt vmcnt(0)" ::: "memory"); }  \
    __builtin_amdgcn_sched_barrier(0);                                      \
    __builtin_amdgcn_s_barrier();                                           \
    if ((t) + 1 < NK) LOAD_A(Aoth, (t) + 1)                                 \
    if ((t) + 2 < NK) {                                                     \
      const int stslot = ((t) + 2) % 3;                                     \
      STAGE_B(stslot, (t) + 2)                                              \
    }                                                                       \
    __builtin_amdgcn_sched_barrier(0); /* pin loads above the MFMAs */      \
    bf16x8 Bf[8];                                                           \
    const int rdslot = (t) % 3;                                             \
    _Pragma("unroll")                                                       \
    for (int f = 0; f < 8; ++f)                                             \
      Bf[f] = *reinterpret_cast<const bf16x8*>(                             \
          &GB[rdslot][f * 512 + lane * 8]);                                 \
    MFMA_TAP(Acur, Bf)                                                      \
  }

  // Prologue: queue = [B0:2][A0:8][B1:2] = 12 outstanding.
  STAGE_B(0, 0)
  LOAD_A(AE, 0)
  STAGE_B(1, 1)

#pragma unroll 1
  for (int j = 0; j < 13; ++j) {
    const int t = 2 * j;
    TILE_STEP(AE, AO, t)
    TILE_STEP(AO, AE, t + 1)
  }
  TILE_STEP(AE, AO, 26)   // tail tap (vmcnt(0) path)

#undef LOAD_A
#undef STAGE_B
#undef MFMA_TAP
#undef TILE_STEP

  // Store y (bf16). D layout: col = lane&15, row = (lane>>4)*4 + r  [m89]
  // (scattered short stores — proven neutral vs coalesced in R17/R20 A/B)
#pragma unroll
  for (int g = 0; g < 4; ++g)
#pragma unroll
    for (int j = 0; j < 4; ++j) {
      const int col = j * 16 + (lane & 15);
#pragma unroll
      for (int r = 0; r < 4; ++r) {
        const int row = n0 + wv * 64 + g * 16 + (lane >> 4) * 4 + r;
        if (row < N_VOX) ((short*)y)[(size_t)row * NCH + col] = f2b(acc[g][j][r]);
      }
    }

  // BN partial sums: per-channel sum and sum-of-squares over this block's rows
  // (zero-padded tail rows contribute 0).
#pragma unroll
  for (int j = 0; j < 4; ++j) {
    float s1 = 0.f, s2 = 0.f;
#pragma unroll
    for (int g = 0; g < 4; ++g)
#pragma unroll
      for (int r = 0; r < 4; ++r) {
        const float v = acc[g][j][r];
        s1 += v;
        s2 += v * v;
      }
    s1 += __shfl_xor(s1, 16); s2 += __shfl_xor(s2, 16);
    s1 += __shfl_xor(s1, 32); s2 += __shfl_xor(s2, 32);
    if (lane < 16) {
      redS[wv][j * 16 + lane] = s1;
      redQ[wv][j * 16 + lane] = s2;
    }
  }
  __syncthreads();
  if (tid < NCH) {
    const float s1 = redS[0][tid] + redS[1][tid] + redS[2][tid] + redS[3][tid];
    const float s2 = redQ[0][tid] + redQ[1][tid] + redQ[2][tid] + redQ[3][tid];
    part[(size_t)blockIdx.x * 128 + tid] = s1;
    part[(size_t)blockIdx.x * 128 + 64 + tid] = s2;
  }
}

// ---------------------------------------------------------------------------
// Reduce per-block partials -> per-channel (a, shift): a = g*rsqrt(var+eps),
// shift = b - mean*a.  Grid: 64 blocks (one per channel) x 256 threads.
__global__ void finalize(const float* __restrict__ part, int nblk,
                         const float* __restrict__ g, const float* __restrict__ b,
                         float* __restrict__ ab) {
  __shared__ float r1[256], r2[256];
  const int c = blockIdx.x;
  const int t = threadIdx.x;
  float s1 = 0.f, s2 = 0.f;
  for (int bb = t; bb < nblk; bb += 256) {
    s1 += part[(size_t)bb * 128 + c];
    s2 += part[(size_t)bb * 128 + 64 + c];
  }
  r1[t] = s1; r2[t] = s2;
  __syncthreads();
  for (int off = 128; off > 0; off >>= 1) {
    if (t < off) { r1[t] += r1[t + off]; r2[t] += r2[t + off]; }
    __syncthreads();
  }
  if (t == 0) {
    const float m = r1[0] / (float)N_VOX;
    const float v = r2[0] / (float)N_VOX - m * m;
    const float a = g[c] * rsqrtf(v + 1e-5f);
    const float sh = b[c] - m * a;
    ab[c] = a;
    ab[64 + c] = sh;
  }
}

// ---------------------------------------------------------------------------
// z[n,c] = lrelu(y[n,c]*a[c]+s[c]) as bf16; row N (sentinel) = 0.
__global__ void bn_act(const bf16* __restrict__ y, const float* __restrict__ ab,
                       bf16* __restrict__ z) {
  const size_t i = ((size_t)blockIdx.x * 256 + threadIdx.x) * 8;
  if (i >= (size_t)(N_VOX + 1) * NCH) return;
  const int col = (int)(i & 63);
  bf16x8 o;
  if (i < (size_t)N_VOX * NCH) {
    const bf16x8 v = *reinterpret_cast<const bf16x8*>((const short*)y + i);
#pragma unroll
    for (int e = 0; e < 8; ++e) {
      float x = b2f(v[e]) * ab[col + e] + ab[64 + col + e];
      x = x < 0.f ? 0.01f * x : x;
      o[e] = f2b(x);
    }
  } else {
#pragma unroll
    for (int e = 0; e < 8; ++e) o[e] = 0;
  }
  *reinterpret_cast<bf16x8*>((short*)z + i) = o;
}

// ---------------------------------------------------------------------------
// out[n,c] = lrelu( feats[n,c] + lrelu(y[n,c]*a[c]+s[c]) ) as f32.
// Grid exact: N*C/2048 = 3125 blocks, no tail.
__global__ void bn_act_res(const bf16* __restrict__ y, const float* __restrict__ ab,
                           const float* __restrict__ feats, float* __restrict__ out) {
  const size_t i = ((size_t)blockIdx.x * 256 + threadIdx.x) * 8;
  const int col = (int)(i & 63);
  const bf16x8 v = *reinterpret_cast<const bf16x8*>((const short*)y + i);
  const f32x4 s0 = *reinterpret_cast<const f32x4*>(feats + i);
  const f32x4 s1 = *reinterpret_cast<const f32x4*>(feats + i + 4);
  f32x4 o0, o1;
#pragma unroll
  for (int e = 0; e < 8; ++e) {
    float x = b2f(v[e]) * ab[col + e] + ab[64 + col + e];
    x = x < 0.f ? 0.01f * x : x;                    // lrelu(bn2)
    float r = (e < 4 ? s0[e] : s1[e - 4]) + x;      // + skip
    r = r < 0.f ? 0.01f * r : r;                    // final lrelu
    if (e < 4) o0[e] = r; else o1[e - 4] = r;
  }
  *reinterpret_cast<f32x4*>(out + i) = o0;
  *reinterpret_cast<f32x4*>(out + i + 4) = o1;
}

// ---------------------------------------------------------------------------
extern "C" void kernel_launch(void* const* d_in, const int* in_sizes, int n_in,
                              void* d_out, int out_size, void* d_ws, size_t ws_size,
                              hipStream_t stream) {
  const float* feats = (const float*)d_in[0];
  const float* W1 = (const float*)d_in[1];
  const float* g1 = (const float*)d_in[2];
  const float* b1 = (const float*)d_in[3];
  const float* W2 = (const float*)d_in[4];
  const float* g2 = (const float*)d_in[5];
  const float* b2 = (const float*)d_in[6];
  const int* nbr = (const int*)d_in[7];
  float* out = (float*)d_out;

  char* p = (char*)d_ws;
  bf16* fbf = (bf16*)p; p += (size_t)(N_VOX + 1) * NCH * 2;   // 12.80 MB
  bf16* ybf = (bf16*)p; p += (size_t)N_VOX * NCH * 2;         // 12.80 MB
  bf16* z = (bf16*)p;   p += (size_t)(N_VOX + 1) * NCH * 2;   // 12.80 MB
  bf16* wp1 = (bf16*)p; p += 442368;
  bf16* wp2 = (bf16*)p; p += 442368;
  float* part = (float*)p; p += (size_t)NBLK * 128 * 4;       // 200 KB
  float* ab1 = (float*)p; p += 512;
  float* ab2 = (float*)p; p += 512;

  const int cast_blocks = (int)(((size_t)(N_VOX + 1) * NCH / 8 + 255) / 256);  // 3126

  cast_feats<<<cast_blocks, 256, 0, stream>>>(feats, fbf);
  pack_w<<<108, 256, 0, stream>>>(W1, W2, wp1, wp2);

  conv_mfma<<<NBLK, 256, 0, stream>>>(fbf, wp1, nbr, ybf, part);
  finalize<<<64, 256, 0, stream>>>(part, NBLK, g1, b1, ab1);
  bn_act<<<cast_blocks, 256, 0, stream>>>(ybf, ab1, z);

  conv_mfma<<<NBLK, 256, 0, stream>>>(z, wp2, nbr, ybf, part);
  finalize<<<64, 256, 0, stream>>>(part, NBLK, g2, b2, ab2);
  bn_act_res<<<(N_VOX * NCH / 8) / 256, 256, 0, stream>>>(ybf, ab2, feats, out);
}